// Round 7
// baseline (1330.116 us; speedup 1.0000x reference)
//
#include <hip/hip_runtime.h>
#include <hip/hip_bf16.h>
#include <stdint.h>

typedef unsigned short ushort_t;
typedef __bf16 bf16x8 __attribute__((ext_vector_type(8)));
typedef float    f32x4 __attribute__((ext_vector_type(4)));
typedef float   f32x16 __attribute__((ext_vector_type(16)));
typedef unsigned short us4 __attribute__((ext_vector_type(4)));
typedef unsigned int ui4 __attribute__((ext_vector_type(4)));

#define QK_SCALE 0.12751744f   /* log2(e) / sqrt(128) : folded into Q so softmax uses exp2 */
#define NEG_BIG  -1e30f

__device__ __forceinline__ unsigned short f2bf(float f) {
    union { float f; unsigned int u; } v; v.f = f;
    unsigned int u = v.u;
    return (unsigned short)((u + 0x7FFFu + ((u >> 16) & 1u)) >> 16);  // RNE
}

// HW packed convert: dst.lo = bf16(a), dst.hi = bf16(b)   (no builtin on gfx950)
__device__ __forceinline__ unsigned int pk2bf(float a, float b) {
    unsigned int r;
    asm("v_cvt_pk_bf16_f32 %0, %1, %2" : "=v"(r) : "v"(a), "v"(b));
    return r;
}

// async global->LDS, 16B per lane. LDS dest is wave-uniform base + lane*16.
__device__ __forceinline__ void gload16(const void* g, void* l) {
    __builtin_amdgcn_global_load_lds(
        (__attribute__((address_space(1))) void*)(uintptr_t)g,
        (__attribute__((address_space(3))) void*)(uint32_t)(uintptr_t)l,
        16, 0, 0);
}

// ---------------- prep kernels ----------------

__global__ __launch_bounds__(256) void cvt_bf16_kernel(
    const float4* __restrict__ in, us4* __restrict__ out, int n4) {
    int i = blockIdx.x * 256 + threadIdx.x;
    if (i >= n4) return;
    float4 v = in[i];
    us4 o; o[0] = f2bf(v.x); o[1] = f2bf(v.y); o[2] = f2bf(v.z); o[3] = f2bf(v.w);
    out[i] = o;
}

// in [R][C] fp32  ->  out [C][R] bf16   (64x64 LDS tile transpose)
__global__ __launch_bounds__(256) void transpose_bf16(
    const float* __restrict__ in, ushort_t* __restrict__ out, int R, int C) {
    __shared__ float t[64][65];
    int c0 = blockIdx.x * 64, r0 = blockIdx.y * 64;
    int cc = threadIdx.x & 63, rr = threadIdx.x >> 6;
#pragma unroll
    for (int i = 0; i < 16; ++i) {
        int r = i * 4 + rr;
        t[r][cc] = in[(size_t)(r0 + r) * C + c0 + cc];
    }
    __syncthreads();
#pragma unroll
    for (int i = 0; i < 16; ++i) {
        int r = i * 4 + rr;
        out[(size_t)(c0 + r) * R + r0 + cc] = f2bf(t[cc][r]);
    }
}

// rope table: [L][64] of (cos, sin)
__global__ __launch_bounds__(256) void rope_table_kernel(float2* __restrict__ rope) {
    int i = blockIdx.x * 256 + threadIdx.x;     // L*64 = 131072 exactly
    int l = i >> 6, j = i & 63;
    float inv = exp2f((float)j * -0.20762050593046f);  // 10000^(-j/64)
    float f = (float)l * inv;
    rope[i] = make_float2(cosf(f), sinf(f));
}

// ---------------- GEMM:  C[M][N] = A[M][K] * Bt[N][K]^T  (bf16 in, fp32 acc) ----------------

template <int EPI>
__global__ __launch_bounds__(256, 2)
void gemm_bt(const ushort_t* __restrict__ A, const ushort_t* __restrict__ Bt,
             int M, int N, int K,
             float* __restrict__ C,
             ushort_t* __restrict__ Qb, ushort_t* __restrict__ Kb,
             ushort_t* __restrict__ Vt, const float2* __restrict__ rope) {
    constexpr int MI = (EPI == 1) ? 2 : 4;
    constexpr int NI = (EPI == 1) ? 8 : 4;

    __shared__ __attribute__((aligned(16))) ushort_t ldsA[128 * 64];
    __shared__ __attribute__((aligned(16))) ushort_t ldsB[128 * 64];
    char* ldsAc = (char*)ldsA;
    char* ldsBc = (char*)ldsB;

    const int tid  = threadIdx.x;
    const int lane = tid & 63, wid = tid >> 6;
    const int lr = lane & 15, lg = lane >> 4;

    const int nbn = N >> 7;
    const int nwg = gridDim.x;
    const int bid = blockIdx.x;
    const int wg  = (bid & 7) * (nwg >> 3) + (bid >> 3);   // XCD-contiguous chunks
    const int bm  = wg / nbn, bn = wg % nbn;

    const int arow0 = (EPI == 1) ? wid * 32 : (wid >> 1) * 64;
    const int bcol0 = (EPI == 1) ? 0        : (wid & 1) * 64;

    const int colb = ((tid & 7) << 4) ^ (((tid >> 3) & 7) << 4);
    const int rowi = tid >> 3;                       // 0..31
    const char* Ap = (const char*)A + ((size_t)(bm * 128 + rowi) * K) * 2 + colb;
    const char* Bp = (const char*)Bt + ((size_t)(bn * 128 + rowi) * K) * 2 + colb;
    const size_t rstr = (size_t)32 * K * 2;
    char* ldA = ldsAc + wid * 1024;
    char* ldB = ldsBc + wid * 1024;

    f32x4 acc[MI][NI];
#pragma unroll
    for (int i = 0; i < MI; ++i)
#pragma unroll
        for (int j = 0; j < NI; ++j) acc[i][j] = (f32x4){0.f, 0.f, 0.f, 0.f};

    for (int k0 = 0; k0 < K; k0 += 64) {
#pragma unroll
        for (int r = 0; r < 4; ++r) {
            gload16(Ap + r * rstr + (size_t)k0 * 2, ldA + r * 4096);
            gload16(Bp + r * rstr + (size_t)k0 * 2, ldB + r * 4096);
        }
        __syncthreads();
#pragma unroll
        for (int kk = 0; kk < 2; ++kk) {
            bf16x8 af[MI], bfv[NI];
#pragma unroll
            for (int mi = 0; mi < MI; ++mi) {
                int row = arow0 + mi * 16 + lr;
                int off = (row << 7) + kk * 64 + lg * 16;
                off ^= (row & 7) << 4;
                af[mi] = *(const bf16x8*)(ldsAc + off);
            }
#pragma unroll
            for (int ni = 0; ni < NI; ++ni) {
                int row = bcol0 + ni * 16 + lr;
                int off = (row << 7) + kk * 64 + lg * 16;
                off ^= (row & 7) << 4;
                bfv[ni] = *(const bf16x8*)(ldsBc + off);
            }
#pragma unroll
            for (int mi = 0; mi < MI; ++mi)
#pragma unroll
                for (int ni = 0; ni < NI; ++ni)
                    acc[mi][ni] = __builtin_amdgcn_mfma_f32_16x16x32_bf16(
                        af[mi], bfv[ni], acc[mi][ni], 0, 0, 0);
        }
        __syncthreads();
    }

    if constexpr (EPI == 0) {
#pragma unroll
        for (int mi = 0; mi < MI; ++mi) {
            int gr0 = bm * 128 + arow0 + mi * 16 + lg * 4;
#pragma unroll
            for (int ni = 0; ni < NI; ++ni) {
                int gc = bn * 128 + bcol0 + ni * 16 + lr;
#pragma unroll
                for (int r = 0; r < 4; ++r)
                    C[(size_t)(gr0 + r) * N + gc] = acc[mi][ni][r];
            }
        }
    } else {
        const int which = bn >> 4, h = bn & 15;
#pragma unroll
        for (int mi = 0; mi < MI; ++mi) {
            int gr0 = bm * 128 + arow0 + mi * 16 + lg * 4;   // = b*L + l0 (4 consecutive l)
            int b = gr0 >> 11, l0 = gr0 & 2047;
            if (which == 2) {                                 // V -> [BH][D][L] (transposed)
#pragma unroll
                for (int ni = 0; ni < NI; ++ni) {
                    int d = ni * 16 + lr;
                    us4 pk;
#pragma unroll
                    for (int r = 0; r < 4; ++r) pk[r] = f2bf(acc[mi][ni][r]);
                    *(us4*)(Vt + ((size_t)(b * 16 + h) * 128 + d) * 2048 + l0) = pk;
                }
            } else {                                          // Q/K: rope, -> [BH][L][D]
                ushort_t* dst = (which == 0) ? Qb : Kb;
                const float sc = (which == 0) ? QK_SCALE : 1.0f;
#pragma unroll
                for (int ni = 0; ni < 4; ++ni) {
                    int j = ni * 16 + lr;                     // d < 64 ; pair at d+64 = frag ni+4
#pragma unroll
                    for (int r = 0; r < 4; ++r) {
                        float2 cs = rope[(size_t)(l0 + r) * 64 + j];
                        float x1 = acc[mi][ni][r], x2 = acc[mi][ni + 4][r];
                        size_t base = ((size_t)(b * 16 + h) * 2048 + (l0 + r)) * 128;
                        dst[base + j]      = f2bf((x1 * cs.x - x2 * cs.y) * sc);
                        dst[base + j + 64] = f2bf((x2 * cs.x + x1 * cs.y) * sc);
                    }
                }
            }
        }
    }
}

// ---------------- causal flash attention (swapped-operand, in-register softmax) ----------------
// Q,K: [BH][L][128] bf16 (Q pre-scaled); V^T: [BH][128][L] bf16; AO: [B][L][H*128] bf16.
// 1024 blocks x 4 waves. Block owns 4 CONSECUTIVE 32-row slices {4g..4g+3}, one per wave;
// K/V fragments are q-independent, so the 4 waves fetch the SAME lines within a short
// window -> one L2 miss + three L1 hits. No barriers, no LDS; each wave runs the proven
// per-wave dataflow with its own trip count. Groups dispatched longest-first (rank0 -> g15).

__global__ __launch_bounds__(256, 4)
void attn_fwd(const ushort_t* __restrict__ Qb, const ushort_t* __restrict__ Kb,
              const ushort_t* __restrict__ Vt, ushort_t* __restrict__ AO) {
    constexpr int L = 2048;
    const int tid  = threadIdx.x;
    const int lane = tid & 63, wid = tid >> 6;
    const int q_l  = lane & 31;
    const int hi   = (lane >> 5) & 1;

    // 1024 blocks: xcd = bid&7 (head affinity), hl = heads 0..7 on that xcd,
    // rank 0..15 -> group g = 15-rank (longest first). Wave wid -> slice 4g+wid.
    const int bid  = blockIdx.x;
    const int j    = bid >> 3;
    const int hl   = j & 7;
    const int rank = j >> 3;                    // 0..15
    const int head = (bid & 7) * 8 + hl;
    const int sl   = (15 - rank) * 4 + wid;     // slice 0..63
    const int q0   = sl * 32;

    const ushort_t* Qh = Qb + (size_t)head * L * 128;
    const ushort_t* Kh = Kb + (size_t)head * L * 128;
    const ushort_t* Vh = Vt + (size_t)head * 128 * L;
    const int b = head >> 4, h = head & 15;

    // Q^T B-frags hoisted: lane holds Q[q0+q_l][sb*16 + hi*8 + 0..7]
    bf16x8 qf[8];
#pragma unroll
    for (int sb = 0; sb < 8; ++sb)
        qf[sb] = *(const bf16x8*)(Qh + (size_t)(q0 + q_l) * 128 + sb * 16 + hi * 8);

    f32x16 o[4];
#pragma unroll
    for (int d0 = 0; d0 < 4; ++d0) o[d0] = (f32x16)(0.f);
    float m_ = -__builtin_inff(), l_ = 0.f;

    // K(0) preload
    bf16x8 kf[8];
#pragma unroll
    for (int sb = 0; sb < 8; ++sb)
        kf[sb] = *(const bf16x8*)(Kh + (size_t)q_l * 128 + sb * 16 + hi * 8);

    const int ntile = sl + 1;
    for (int t = 0; t < ntile; ++t) {
        const int k0 = t * 32;

        // ---- V loads for THIS tile issued first (consumed after softmax) ----
        bf16x8 vf[8];
#pragma unroll
        for (int d0 = 0; d0 < 4; ++d0)
#pragma unroll
            for (int ks = 0; ks < 2; ++ks)
                vf[d0 * 2 + ks] = *(const bf16x8*)(Vh + (size_t)(d0 * 32 + q_l) * L + k0 + ks * 16 + hi * 8);

        // ---- S^T = K * Q^T : two accumulator chains (kf already in registers) ----
        __builtin_amdgcn_s_setprio(1);
        f32x16 sa = (f32x16)(0.f), sb2 = (f32x16)(0.f);
#pragma unroll
        for (int sb = 0; sb < 8; sb += 2) {
            sa  = __builtin_amdgcn_mfma_f32_32x32x16_bf16(kf[sb],     qf[sb],     sa,  0, 0, 0);
            sb2 = __builtin_amdgcn_mfma_f32_32x32x16_bf16(kf[sb + 1], qf[sb + 1], sb2, 0, 0, 0);
        }
        f32x16 s = sa + sb2;
        __builtin_amdgcn_s_setprio(0);

        // ---- K(t+1) prefetch: latency hides under softmax + PV of tile t ----
        if (t + 1 < ntile) {
            const int kn = k0 + 32;
#pragma unroll
            for (int sb = 0; sb < 8; ++sb)
                kf[sb] = *(const bf16x8*)(Kh + (size_t)(kn + q_l) * 128 + sb * 16 + hi * 8);
        }

        // causal mask on the diagonal tile: k = k0 + crow(reg,hi), q = q0 + q_l, k0==q0
        if (t == ntile - 1) {
#pragma unroll
            for (int r = 0; r < 16; ++r) {
                int kk = (r & 3) + 8 * (r >> 2) + 4 * hi;
                if (kk > q_l) s[r] = NEG_BIG;
            }
        }

        // ---- in-register online softmax (lane owns q-row q0+q_l) ----
        float t8[8];
#pragma unroll
        for (int r = 0; r < 8; ++r) t8[r] = fmaxf(s[r], s[r + 8]);
#pragma unroll
        for (int r = 0; r < 4; ++r) t8[r] = fmaxf(t8[r], t8[r + 4]);
        float tmax = fmaxf(fmaxf(t8[0], t8[1]), fmaxf(t8[2], t8[3]));
        tmax = fmaxf(tmax, __shfl_xor(tmax, 32, 64));     // full 32-k row max

        if (!__all(tmax <= m_ + 8.f)) {                   // defer-max THR=8 (log2 units)
            float mn = fmaxf(m_, tmax);
            float alpha = exp2f(m_ - mn);
            m_ = mn;
            l_ *= alpha;
#pragma unroll
            for (int d0 = 0; d0 < 4; ++d0)
#pragma unroll
                for (int r = 0; r < 16; ++r) o[d0][r] *= alpha;
        }

        float p[16];
        float rs = 0.f;
#pragma unroll
        for (int r = 0; r < 16; ++r) { p[r] = exp2f(s[r] - m_); rs += p[r]; }
        rs += __shfl_xor(rs, 32, 64);
        l_ += rs;

        // ---- pack P -> bf16 pairs (HW cvt_pk); assemble P^T B-frags via partner exchange ----
        unsigned int pk[8];
#pragma unroll
        for (int i = 0; i < 8; ++i) pk[i] = pk2bf(p[2 * i], p[2 * i + 1]);
        unsigned int po[8];
#pragma unroll
        for (int i = 0; i < 8; ++i) po[i] = __shfl_xor(pk[i], 32, 64);

        bf16x8 pf[2];
#pragma unroll
        for (int ks = 0; ks < 2; ++ks) {
            ui4 dw;
            dw[0] = hi ? po[ks * 4 + 2] : pk[ks * 4 + 0];
            dw[1] = hi ? po[ks * 4 + 3] : pk[ks * 4 + 1];
            dw[2] = hi ? pk[ks * 4 + 2] : po[ks * 4 + 0];
            dw[3] = hi ? pk[ks * 4 + 3] : po[ks * 4 + 1];
            pf[ks] = __builtin_bit_cast(bf16x8, dw);
        }

        // ---- O^T += V^T * P^T : vf long in flight; MFMAs back-to-back ----
        __builtin_amdgcn_s_setprio(1);
#pragma unroll
        for (int d0 = 0; d0 < 4; ++d0)
#pragma unroll
            for (int ks = 0; ks < 2; ++ks)
                o[d0] = __builtin_amdgcn_mfma_f32_32x32x16_bf16(vf[d0 * 2 + ks], pf[ks], o[d0], 0, 0, 0);
        __builtin_amdgcn_s_setprio(0);
    }

    // ---- epilogue: lane owns q-row q0+q_l entirely; d = d0*32 + (g*8 + hi*4 + 0..3) ----
    const float inv = 1.f / l_;
    const size_t rowbase = ((size_t)(b * 2048 + q0 + q_l)) * 2048 + h * 128;
#pragma unroll
    for (int d0 = 0; d0 < 4; ++d0)
#pragma unroll
        for (int g = 0; g < 4; ++g) {
            us4 v;
#pragma unroll
            for (int r = 0; r < 4; ++r) v[r] = f2bf(o[d0][g * 4 + r] * inv);
            *(us4*)(AO + rowbase + d0 * 32 + g * 8 + hi * 4) = v;
        }
}

// ---------------- launcher ----------------

extern "C" void kernel_launch(void* const* d_in, const int* in_sizes, int n_in,
                              void* d_out, int out_size, void* d_ws, size_t ws_size,
                              hipStream_t stream) {
    const float* x    = (const float*)d_in[0];   // [4,2048,2048]
    const float* Wqkv = (const float*)d_in[1];   // [2048,6144]
    const float* Wo   = (const float*)d_in[2];   // [2048,2048]
    float* out = (float*)d_out;                  // [4,2048,2048] fp32

    char* w = (char*)d_ws;
    ushort_t* xb   = (ushort_t*)(w);               // x bf16             33,554,432 B
    ushort_t* W1t  = (ushort_t*)(w + 33554432);    // Wqkv^T bf16        25,165,824 B
    ushort_t* Wot  = (ushort_t*)(w + 58720256);    // Wo^T bf16           8,388,608 B
    ushort_t* Qb   = (ushort_t*)(w + 67108864);    // Q roped [BH][L][D] 33,554,432 B
    ushort_t* Kbf  = (ushort_t*)(w + 100663296);   // K roped [BH][L][D] 33,554,432 B
    ushort_t* Vt   = (ushort_t*)(w + 134217728);   // V^T    [BH][D][L]  33,554,432 B
    ushort_t* AO   = (ushort_t*)(w + 167772160);   // attn out bf16      33,554,432 B
    float2*   rope = (float2*)(w + 201326592);     // [L][64] cos/sin     1,048,576 B

    cvt_bf16_kernel<<<16384, 256, 0, stream>>>((const float4*)x, (us4*)xb, 4194304);
    transpose_bf16<<<dim3(96, 32), 256, 0, stream>>>(Wqkv, W1t, 2048, 6144);
    transpose_bf16<<<dim3(32, 32), 256, 0, stream>>>(Wo, Wot, 2048, 2048);
    rope_table_kernel<<<512, 256, 0, stream>>>(rope);

    // qkv GEMM + fused rope/reshape epilogue
    gemm_bt<1><<<3072, 256, 0, stream>>>(xb, W1t, 8192, 6144, 2048,
                                         nullptr, Qb, Kbf, Vt, rope);
    // causal flash attention: 4-wave blocks, 4 consecutive slices, longest-first
    attn_fwd<<<1024, 256, 0, stream>>>(Qb, Kbf, Vt, AO);
    // output projection
    gemm_bt<0><<<1024, 256, 0, stream>>>(AO, Wot, 8192, 2048, 2048,
                                         out, nullptr, nullptr, nullptr, nullptr);
}

// Round 8
// 807.119 us; speedup vs baseline: 1.6480x; 1.6480x over previous
//
#include <hip/hip_runtime.h>
#include <hip/hip_bf16.h>
#include <stdint.h>

typedef unsigned short ushort_t;
typedef __bf16 bf16x8 __attribute__((ext_vector_type(8)));
typedef float    f32x4 __attribute__((ext_vector_type(4)));
typedef float   f32x16 __attribute__((ext_vector_type(16)));
typedef unsigned short us4 __attribute__((ext_vector_type(4)));
typedef unsigned int ui4 __attribute__((ext_vector_type(4)));

#define QK_SCALE 0.12751744f   /* log2(e) / sqrt(128) : folded into Q so softmax uses exp2 */
#define NEG_BIG  -1e30f

#define VMCNT6() asm volatile("s_waitcnt vmcnt(6)" ::: "memory")
#define VMCNT0() asm volatile("s_waitcnt vmcnt(0)" ::: "memory")
#define BARRIER() do { asm volatile("" ::: "memory"); __builtin_amdgcn_s_barrier(); asm volatile("" ::: "memory"); } while (0)
#define MFMA16(d, a, b) d = __builtin_amdgcn_mfma_f32_16x16x32_bf16(a, b, d, 0, 0, 0)

__device__ __forceinline__ unsigned short f2bf(float f) {
    union { float f; unsigned int u; } v; v.f = f;
    unsigned int u = v.u;
    return (unsigned short)((u + 0x7FFFu + ((u >> 16) & 1u)) >> 16);  // RNE
}

// HW packed convert: dst.lo = bf16(a), dst.hi = bf16(b)
__device__ __forceinline__ unsigned int pk2bf(float a, float b) {
    unsigned int r;
    asm("v_cvt_pk_bf16_f32 %0, %1, %2" : "=v"(r) : "v"(a), "v"(b));
    return r;
}

// async global->LDS, 16B per lane. LDS dest is wave-uniform base + lane*16.
__device__ __forceinline__ void gload16(const void* g, void* l) {
    __builtin_amdgcn_global_load_lds(
        (__attribute__((address_space(1))) void*)(uintptr_t)g,
        (__attribute__((address_space(3))) void*)(uint32_t)(uintptr_t)l,
        16, 0, 0);
}

// ---------------- prep kernels ----------------

__global__ __launch_bounds__(256) void cvt_bf16_kernel(
    const float4* __restrict__ in, us4* __restrict__ out, int n4) {
    int i = blockIdx.x * 256 + threadIdx.x;
    if (i >= n4) return;
    float4 v = in[i];
    us4 o; o[0] = f2bf(v.x); o[1] = f2bf(v.y); o[2] = f2bf(v.z); o[3] = f2bf(v.w);
    out[i] = o;
}

// generic: in [R][C] fp32 -> out [C][R] bf16
__global__ __launch_bounds__(256) void transpose_bf16(
    const float* __restrict__ in, ushort_t* __restrict__ out, int R, int C) {
    __shared__ float t[64][65];
    int c0 = blockIdx.x * 64, r0 = blockIdx.y * 64;
    int cc = threadIdx.x & 63, rr = threadIdx.x >> 6;
#pragma unroll
    for (int i = 0; i < 16; ++i) {
        int r = i * 4 + rr;
        t[r][cc] = in[(size_t)(r0 + r) * C + c0 + cc];
    }
    __syncthreads();
#pragma unroll
    for (int i = 0; i < 16; ++i) {
        int r = i * 4 + rr;
        out[(size_t)(c0 + r) * R + r0 + cc] = f2bf(t[cc][r]);
    }
}

// Wqkv transpose with Q/K head-dim bit-permutation: out col p pairs with p+16
// (orig pairs d,d+64). orig(p) = (p&15) | (((p>>5)&3)<<4) | (((p>>4)&1)<<6).
// QK^T is invariant to a consistent d-permutation of Q and K; V left unpermuted.
__global__ __launch_bounds__(256) void transpose_wqkv(
    const float* __restrict__ in /*[2048][6144]*/, ushort_t* __restrict__ out /*[6144][2048]*/) {
    __shared__ float t[64][65];
    int c0 = blockIdx.x * 64, r0 = blockIdx.y * 64;
    int cc = threadIdx.x & 63, rr = threadIdx.x >> 6;
    int n = c0 + cc;
    int which = n >> 11;
    int src = n;
    if (which < 2) {
        int h = (n >> 7) & 15, p = n & 127;
        int po = (p & 15) | (((p >> 5) & 3) << 4) | (((p >> 4) & 1) << 6);
        src = (which << 11) + (h << 7) + po;
    }
#pragma unroll
    for (int i = 0; i < 16; ++i) {
        int r = i * 4 + rr;
        t[r][cc] = in[(size_t)(r0 + r) * 6144 + src];
    }
    __syncthreads();
#pragma unroll
    for (int i = 0; i < 16; ++i) {
        int r = i * 4 + rr;
        out[(size_t)(c0 + r) * 2048 + r0 + cc] = f2bf(t[cc][r]);
    }
}

// rope table: [L][64] of (cos, sin)
__global__ __launch_bounds__(256) void rope_table_kernel(float2* __restrict__ rope) {
    int i = blockIdx.x * 256 + threadIdx.x;     // L*64 = 131072 exactly
    int l = i >> 6, j = i & 63;
    float inv = exp2f((float)j * -0.20762050593046f);  // 10000^(-j/64)
    float f = (float)l * inv;
    rope[i] = make_float2(cosf(f), sinf(f));
}

// ---------------- 256x256 8-phase GEMM: C[M][N] = A[M][K] * Bt[N][K]^T ----------------
// BK=64, 512 thr (8 waves, 2M x 4N), wave tile 128x64. LDS 128 KiB: 2 buffers x
// (A0|A1|B0|B1 halves of 128x64 bf16, XOR-swizzled rows). Counted vmcnt(6) at phases
// 4/8, raw s_barrier (no __syncthreads drain). Staging only overwrites regions whose
// last reader finished >=1 barrier earlier (consumption map in round notes).
// EPI 0: fp32 C. EPI 1: qkv epilogue (lane-local rope via permuted Q/K cols; V^T).

template <int EPI>
__global__ __launch_bounds__(512, 2)
void gemm256(const ushort_t* __restrict__ A, const ushort_t* __restrict__ Bt,
             int M, int N, int K,
             float* __restrict__ C,
             ushort_t* __restrict__ Qb, ushort_t* __restrict__ Kb,
             ushort_t* __restrict__ Vt, const float2* __restrict__ rope) {
    __shared__ __attribute__((aligned(16))) char lds[131072];

    const int tid  = threadIdx.x;
    const int lane = tid & 63, wid = tid >> 6;
    const int lr = lane & 15, lg = lane >> 4;
    const int wr = wid >> 2, wc = wid & 3;        // wave grid 2(M) x 4(N)

    const int nbn = N >> 8;
    const int nwg = gridDim.x;
    const int bid = blockIdx.x;
    const int wg  = (bid & 7) * (nwg >> 3) + (bid >> 3);   // XCD-contiguous
    const int bm  = wg / nbn, bn = wg % nbn;

    // staging: chunk = 64 rows x 64 cols bf16 (8 KB = 512 thr x 16 B)
    const int srow = tid >> 3;                                   // 0..63
    const int scol = ((tid & 7) << 4) ^ ((srow & 7) << 4);       // pre-swizzled src col
    const char* Asrc = (const char*)A + ((size_t)(bm * 256 + srow) * K) * 2 + scol;
    const char* Bsrc = (const char*)Bt + ((size_t)(bn * 256 + srow) * K) * 2 + scol;
    const size_t rowK2 = (size_t)K * 2;

    // reg: 0=A0,1=A1,2=B0,3=B1 (each 16 KB); ch: 0/1 (64-row chunk); kt: K-tile
    auto STG = [&](int bu, int reg, int ch, int kt) {
        const char* s = (reg < 2 ? Asrc : Bsrc) +
                        (size_t)((reg & 1) * 128 + ch * 64) * rowK2 + (size_t)kt * 128;
        gload16(s, lds + bu * 65536 + reg * 16384 + ch * 8192 + wid * 1024);
    };
    auto RDA = [&](int bu, int mi, int kk) -> bf16x8 {
        int rowl = mi * 16 + lr;                                 // within wave's A-half
        int off = (rowl << 7) + kk * 64 + lg * 16;
        off ^= (rowl & 7) << 4;
        return *(const bf16x8*)(lds + bu * 65536 + wr * 16384 + off);
    };
    auto RDB = [&](int bu, int ni, int kk) -> bf16x8 {
        int rowb = wc * 64 + ni * 16 + lr;                       // 0..255
        int off = ((rowb & 127) << 7) + kk * 64 + lg * 16;
        off ^= (rowb & 7) << 4;
        return *(const bf16x8*)(lds + bu * 65536 + 32768 + (rowb >> 7) * 16384 + off);
    };

    f32x4 acc[8][4];
#pragma unroll
    for (int m = 0; m < 8; ++m)
#pragma unroll
        for (int n = 0; n < 4; ++n) acc[m][n] = (f32x4){0.f, 0.f, 0.f, 0.f};

    bf16x8 aLo[4][2], aHi[4][2], bF[2][2];

    // ---- prologue: tile0 fully (8 chunks) + tile1 A+B0 (6 chunks) ----
#pragma unroll
    for (int reg = 0; reg < 4; ++reg) { STG(0, reg, 0, 0); STG(0, reg, 1, 0); }
#pragma unroll
    for (int reg = 0; reg < 3; ++reg) { STG(1, reg, 0, 1); STG(1, reg, 1, 1); }
    VMCNT6();
    BARRIER();

    const int NIT = K / 128;                     // iterations (2 K-tiles each)
    for (int i = 0; i < NIT; ++i) {
        const int te = 2 * i, to = 2 * i + 1;
        const bool g = (i + 1 < NIT);

        // P1: tile te quadrant (mi0-3, ni0-1); stage buf1.B1 of tile 'to'
#pragma unroll
        for (int m = 0; m < 4; ++m) { aLo[m][0] = RDA(0, m, 0); aLo[m][1] = RDA(0, m, 1); }
#pragma unroll
        for (int n = 0; n < 2; ++n) { bF[n][0] = RDB(0, n, 0); bF[n][1] = RDB(0, n, 1); }
        STG(1, 3, 0, to); STG(1, 3, 1, to);
        BARRIER();
        __builtin_amdgcn_s_setprio(1);
#pragma unroll
        for (int kk = 0; kk < 2; ++kk)
#pragma unroll
            for (int m = 0; m < 4; ++m)
#pragma unroll
                for (int n = 0; n < 2; ++n) MFMA16(acc[m][n], aLo[m][kk], bF[n][kk]);
        __builtin_amdgcn_s_setprio(0);
        BARRIER();

        // P2: (mi4-7, ni0-1); stage buf0.A0c0, A1c0 of te+2
#pragma unroll
        for (int m = 0; m < 4; ++m) { aHi[m][0] = RDA(0, 4 + m, 0); aHi[m][1] = RDA(0, 4 + m, 1); }
        if (g) { STG(0, 0, 0, te + 2); STG(0, 1, 0, te + 2); }
        BARRIER();
        __builtin_amdgcn_s_setprio(1);
#pragma unroll
        for (int kk = 0; kk < 2; ++kk)
#pragma unroll
            for (int m = 0; m < 4; ++m)
#pragma unroll
                for (int n = 0; n < 2; ++n) MFMA16(acc[4 + m][n], aHi[m][kk], bF[n][kk]);
        __builtin_amdgcn_s_setprio(0);
        BARRIER();

        // P3: (mi0-3, ni2-3); stage buf0.A0c1, A1c1 of te+2
#pragma unroll
        for (int n = 0; n < 2; ++n) { bF[n][0] = RDB(0, 2 + n, 0); bF[n][1] = RDB(0, 2 + n, 1); }
        if (g) { STG(0, 0, 1, te + 2); STG(0, 1, 1, te + 2); }
        BARRIER();
        __builtin_amdgcn_s_setprio(1);
#pragma unroll
        for (int kk = 0; kk < 2; ++kk)
#pragma unroll
            for (int m = 0; m < 4; ++m)
#pragma unroll
                for (int n = 0; n < 2; ++n) MFMA16(acc[m][2 + n], aLo[m][kk], bF[n][kk]);
        __builtin_amdgcn_s_setprio(0);
        BARRIER();

        // P4: (mi4-7, ni2-3); stage buf0.B0 chunks of te+2; vmcnt -> buf1 tile 'to' ready
        if (g) { STG(0, 2, 0, te + 2); STG(0, 2, 1, te + 2); VMCNT6(); } else { VMCNT0(); }
        BARRIER();
        __builtin_amdgcn_s_setprio(1);
#pragma unroll
        for (int kk = 0; kk < 2; ++kk)
#pragma unroll
            for (int m = 0; m < 4; ++m)
#pragma unroll
                for (int n = 0; n < 2; ++n) MFMA16(acc[4 + m][2 + n], aHi[m][kk], bF[n][kk]);
        __builtin_amdgcn_s_setprio(0);
        BARRIER();

        // P5: tile to (buf1) quadrant (mi0-3, ni0-1); stage buf0.B1 of te+2
#pragma unroll
        for (int m = 0; m < 4; ++m) { aLo[m][0] = RDA(1, m, 0); aLo[m][1] = RDA(1, m, 1); }
#pragma unroll
        for (int n = 0; n < 2; ++n) { bF[n][0] = RDB(1, n, 0); bF[n][1] = RDB(1, n, 1); }
        if (g) { STG(0, 3, 0, te + 2); STG(0, 3, 1, te + 2); }
        BARRIER();
        __builtin_amdgcn_s_setprio(1);
#pragma unroll
        for (int kk = 0; kk < 2; ++kk)
#pragma unroll
            for (int m = 0; m < 4; ++m)
#pragma unroll
                for (int n = 0; n < 2; ++n) MFMA16(acc[m][n], aLo[m][kk], bF[n][kk]);
        __builtin_amdgcn_s_setprio(0);
        BARRIER();

        // P6: (mi4-7, ni0-1); stage buf1.A0c0, A1c0 of to+2
#pragma unroll
        for (int m = 0; m < 4; ++m) { aHi[m][0] = RDA(1, 4 + m, 0); aHi[m][1] = RDA(1, 4 + m, 1); }
        if (g) { STG(1, 0, 0, to + 2); STG(1, 1, 0, to + 2); }
        BARRIER();
        __builtin_amdgcn_s_setprio(1);
#pragma unroll
        for (int kk = 0; kk < 2; ++kk)
#pragma unroll
            for (int m = 0; m < 4; ++m)
#pragma unroll
                for (int n = 0; n < 2; ++n) MFMA16(acc[4 + m][n], aHi[m][kk], bF[n][kk]);
        __builtin_amdgcn_s_setprio(0);
        BARRIER();

        // P7: (mi0-3, ni2-3); stage buf1.A0c1, A1c1 of to+2
#pragma unroll
        for (int n = 0; n < 2; ++n) { bF[n][0] = RDB(1, 2 + n, 0); bF[n][1] = RDB(1, 2 + n, 1); }
        if (g) { STG(1, 0, 1, to + 2); STG(1, 1, 1, to + 2); }
        BARRIER();
        __builtin_amdgcn_s_setprio(1);
#pragma unroll
        for (int kk = 0; kk < 2; ++kk)
#pragma unroll
            for (int m = 0; m < 4; ++m)
#pragma unroll
                for (int n = 0; n < 2; ++n) MFMA16(acc[m][2 + n], aLo[m][kk], bF[n][kk]);
        __builtin_amdgcn_s_setprio(0);
        BARRIER();

        // P8: (mi4-7, ni2-3); stage buf1.B0 of to+2; vmcnt -> buf0 tile te+2 ready
        if (g) { STG(1, 2, 0, to + 2); STG(1, 2, 1, to + 2); VMCNT6(); } else { VMCNT0(); }
        BARRIER();
        __builtin_amdgcn_s_setprio(1);
#pragma unroll
        for (int kk = 0; kk < 2; ++kk)
#pragma unroll
            for (int m = 0; m < 4; ++m)
#pragma unroll
                for (int n = 0; n < 2; ++n) MFMA16(acc[4 + m][2 + n], aHi[m][kk], bF[n][kk]);
        __builtin_amdgcn_s_setprio(0);
        BARRIER();
    }

    // ---------------- epilogue ----------------
    if constexpr (EPI == 0) {
#pragma unroll
        for (int m = 0; m < 8; ++m) {
            int gr0 = bm * 256 + wr * 128 + m * 16 + lg * 4;
#pragma unroll
            for (int n = 0; n < 4; ++n) {
                int gc = bn * 256 + wc * 64 + n * 16 + lr;
#pragma unroll
                for (int r = 0; r < 4; ++r)
                    C[(size_t)(gr0 + r) * N + gc] = acc[m][n][r];
            }
        }
    } else {
        // head-chunk: 128 N-cols; wave covers 64 of them ((wc&1) half)
        const int hc = bn * 2 + (wc >> 1);       // 0..47
        const int which = hc >> 4, h = hc & 15;
#pragma unroll
        for (int m = 0; m < 8; ++m) {
            int gr0 = bm * 256 + wr * 128 + m * 16 + lg * 4;   // b*L + l0
            int b = gr0 >> 11, l0 = gr0 & 2047;
            if (which == 2) {                    // V -> [BH][D][L], d unpermuted
#pragma unroll
                for (int n = 0; n < 4; ++n) {
                    int d = (wc & 1) * 64 + n * 16 + lr;
                    us4 pk;
#pragma unroll
                    for (int r = 0; r < 4; ++r) pk[r] = f2bf(acc[m][n][r]);
                    *(us4*)(Vt + ((size_t)(b * 16 + h) * 128 + d) * 2048 + l0) = pk;
                }
            } else {                             // Q/K: rope on lane-local pairs (np, np+1)
                ushort_t* dst = (which == 0) ? Qb : Kb;
                const float sc = (which == 0) ? QK_SCALE : 1.0f;
#pragma unroll
                for (int np = 0; np < 4; np += 2) {
                    int tbl = ((wc & 1) * 2 + (np >> 1)) * 16 + lr;   // orig dim 0..63
                    int p1 = (wc & 1) * 64 + np * 16 + lr;            // permuted d
#pragma unroll
                    for (int r = 0; r < 4; ++r) {
                        float2 cs = rope[(size_t)(l0 + r) * 64 + tbl];
                        float x1 = acc[m][np][r], x2 = acc[m][np + 1][r];
                        size_t base = ((size_t)(b * 16 + h) * 2048 + (l0 + r)) * 128;
                        dst[base + p1]      = f2bf((x1 * cs.x - x2 * cs.y) * sc);
                        dst[base + p1 + 16] = f2bf((x2 * cs.x + x1 * cs.y) * sc);
                    }
                }
            }
        }
    }
}

// ---------------- causal flash attention (R6 kernel, verified 266 us) ----------------
__global__ __attribute__((amdgpu_flat_work_group_size(64, 64), amdgpu_waves_per_eu(2, 2)))
void attn_fwd(const ushort_t* __restrict__ Qb, const ushort_t* __restrict__ Kb,
              const ushort_t* __restrict__ Vt, ushort_t* __restrict__ AO) {
    constexpr int L = 2048;
    const int lane = threadIdx.x;
    const int q_l  = lane & 31;
    const int hi   = lane >> 5;

    const int bid  = blockIdx.x;
    const int j    = bid >> 3;
    const int hl   = j & 7;
    const int rank = j >> 3;                    // 0..63
    const int head = (bid & 7) * 8 + hl;
    const int sl   = 63 - rank;
    const int q0   = sl * 32;

    const ushort_t* Qh = Qb + (size_t)head * L * 128;
    const ushort_t* Kh = Kb + (size_t)head * L * 128;
    const ushort_t* Vh = Vt + (size_t)head * 128 * L;
    const int b = head >> 4, h = head & 15;

    bf16x8 qf[8];
#pragma unroll
    for (int sb = 0; sb < 8; ++sb)
        qf[sb] = *(const bf16x8*)(Qh + (size_t)(q0 + q_l) * 128 + sb * 16 + hi * 8);

    f32x16 o[4];
#pragma unroll
    for (int d0 = 0; d0 < 4; ++d0) o[d0] = (f32x16)(0.f);
    float m_ = -__builtin_inff(), l_ = 0.f;

    bf16x8 kf[8];
#pragma unroll
    for (int sb = 0; sb < 8; ++sb)
        kf[sb] = *(const bf16x8*)(Kh + (size_t)q_l * 128 + sb * 16 + hi * 8);

    const int ntile = sl + 1;
    for (int t = 0; t < ntile; ++t) {
        const int k0 = t * 32;

        bf16x8 vf[8];
#pragma unroll
        for (int d0 = 0; d0 < 4; ++d0)
#pragma unroll
            for (int ks = 0; ks < 2; ++ks)
                vf[d0 * 2 + ks] = *(const bf16x8*)(Vh + (size_t)(d0 * 32 + q_l) * L + k0 + ks * 16 + hi * 8);

        f32x16 sa = (f32x16)(0.f), sb2 = (f32x16)(0.f);
#pragma unroll
        for (int sb = 0; sb < 8; sb += 2) {
            sa  = __builtin_amdgcn_mfma_f32_32x32x16_bf16(kf[sb],     qf[sb],     sa,  0, 0, 0);
            sb2 = __builtin_amdgcn_mfma_f32_32x32x16_bf16(kf[sb + 1], qf[sb + 1], sb2, 0, 0, 0);
        }
        f32x16 s = sa + sb2;

        if (t + 1 < ntile) {
            const int kn = k0 + 32;
#pragma unroll
            for (int sb = 0; sb < 8; ++sb)
                kf[sb] = *(const bf16x8*)(Kh + (size_t)(kn + q_l) * 128 + sb * 16 + hi * 8);
        }

        if (t == ntile - 1) {
#pragma unroll
            for (int r = 0; r < 16; ++r) {
                int kk = (r & 3) + 8 * (r >> 2) + 4 * hi;
                if (kk > q_l) s[r] = NEG_BIG;
            }
        }

        float t8[8];
#pragma unroll
        for (int r = 0; r < 8; ++r) t8[r] = fmaxf(s[r], s[r + 8]);
#pragma unroll
        for (int r = 0; r < 4; ++r) t8[r] = fmaxf(t8[r], t8[r + 4]);
        float tmax = fmaxf(fmaxf(t8[0], t8[1]), fmaxf(t8[2], t8[3]));
        tmax = fmaxf(tmax, __shfl_xor(tmax, 32, 64));

        if (!__all(tmax <= m_ + 8.f)) {
            float mn = fmaxf(m_, tmax);
            float alpha = exp2f(m_ - mn);
            m_ = mn;
            l_ *= alpha;
#pragma unroll
            for (int d0 = 0; d0 < 4; ++d0)
#pragma unroll
                for (int r = 0; r < 16; ++r) o[d0][r] *= alpha;
        }

        float p[16];
        float rs = 0.f;
#pragma unroll
        for (int r = 0; r < 16; ++r) { p[r] = exp2f(s[r] - m_); rs += p[r]; }
        rs += __shfl_xor(rs, 32, 64);
        l_ += rs;

        unsigned int pk[8];
#pragma unroll
        for (int i = 0; i < 8; ++i) pk[i] = pk2bf(p[2 * i], p[2 * i + 1]);
        unsigned int po[8];
#pragma unroll
        for (int i = 0; i < 8; ++i) po[i] = __shfl_xor(pk[i], 32, 64);

        bf16x8 pf[2];
#pragma unroll
        for (int ks = 0; ks < 2; ++ks) {
            ui4 dw;
            dw[0] = hi ? po[ks * 4 + 2] : pk[ks * 4 + 0];
            dw[1] = hi ? po[ks * 4 + 3] : pk[ks * 4 + 1];
            dw[2] = hi ? pk[ks * 4 + 2] : po[ks * 4 + 0];
            dw[3] = hi ? pk[ks * 4 + 3] : po[ks * 4 + 1];
            pf[ks] = __builtin_bit_cast(bf16x8, dw);
        }

#pragma unroll
        for (int d0 = 0; d0 < 4; ++d0)
#pragma unroll
            for (int ks = 0; ks < 2; ++ks)
                o[d0] = __builtin_amdgcn_mfma_f32_32x32x16_bf16(vf[d0 * 2 + ks], pf[ks], o[d0], 0, 0, 0);
    }

    const float inv = 1.f / l_;
    const size_t rowbase = ((size_t)(b * 2048 + q0 + q_l)) * 2048 + h * 128;
#pragma unroll
    for (int d0 = 0; d0 < 4; ++d0)
#pragma unroll
        for (int g = 0; g < 4; ++g) {
            us4 v;
#pragma unroll
            for (int r = 0; r < 4; ++r) v[r] = f2bf(o[d0][g * 4 + r] * inv);
            *(us4*)(AO + rowbase + d0 * 32 + g * 8 + hi * 4) = v;
        }
}

// ---------------- launcher ----------------

extern "C" void kernel_launch(void* const* d_in, const int* in_sizes, int n_in,
                              void* d_out, int out_size, void* d_ws, size_t ws_size,
                              hipStream_t stream) {
    const float* x    = (const float*)d_in[0];   // [4,2048,2048]
    const float* Wqkv = (const float*)d_in[1];   // [2048,6144]
    const float* Wo   = (const float*)d_in[2];   // [2048,2048]
    float* out = (float*)d_out;                  // [4,2048,2048] fp32

    char* w = (char*)d_ws;
    ushort_t* xb   = (ushort_t*)(w);               // x bf16             33,554,432 B
    ushort_t* W1t  = (ushort_t*)(w + 33554432);    // Wqkv^T bf16 (QK-permuted) 25,165,824 B
    ushort_t* Wot  = (ushort_t*)(w + 58720256);    // Wo^T bf16           8,388,608 B
    ushort_t* Qb   = (ushort_t*)(w + 67108864);    // Q roped [BH][L][D'] 33,554,432 B
    ushort_t* Kbf  = (ushort_t*)(w + 100663296);   // K roped [BH][L][D'] 33,554,432 B
    ushort_t* Vt   = (ushort_t*)(w + 134217728);   // V^T    [BH][D][L]  33,554,432 B
    ushort_t* AO   = (ushort_t*)(w + 167772160);   // attn out bf16      33,554,432 B
    float2*   rope = (float2*)(w + 201326592);     // [L][64] cos/sin     1,048,576 B

    cvt_bf16_kernel<<<16384, 256, 0, stream>>>((const float4*)x, (us4*)xb, 4194304);
    transpose_wqkv<<<dim3(96, 32), 256, 0, stream>>>(Wqkv, W1t);
    transpose_bf16<<<dim3(32, 32), 256, 0, stream>>>(Wo, Wot, 2048, 2048);
    rope_table_kernel<<<512, 256, 0, stream>>>(rope);

    // qkv GEMM (256^2 8-phase) + fused rope/reshape epilogue
    gemm256<1><<<768, 512, 0, stream>>>(xb, W1t, 8192, 6144, 2048,
                                        nullptr, Qb, Kbf, Vt, rope);
    // causal flash attention (R6 config)
    attn_fwd<<<4096, 64, 0, stream>>>(Qb, Kbf, Vt, AO);
    // output projection (256^2 8-phase)
    gemm256<0><<<256, 512, 0, stream>>>(AO, Wot, 8192, 2048, 2048,
                                        out, nullptr, nullptr, nullptr, nullptr);
}

// Round 9
// 792.042 us; speedup vs baseline: 1.6793x; 1.0190x over previous
//
#include <hip/hip_runtime.h>
#include <hip/hip_bf16.h>
#include <stdint.h>

typedef unsigned short ushort_t;
typedef __bf16 bf16x8 __attribute__((ext_vector_type(8)));
typedef float    f32x4 __attribute__((ext_vector_type(4)));
typedef float   f32x16 __attribute__((ext_vector_type(16)));
typedef unsigned short us4 __attribute__((ext_vector_type(4)));
typedef unsigned int ui4 __attribute__((ext_vector_type(4)));

#define QK_SCALE 0.12751744f   /* log2(e) / sqrt(128) : folded into Q so softmax uses exp2 */
#define NEG_BIG  -1e30f

#define VMCNT6() asm volatile("s_waitcnt vmcnt(6)" ::: "memory")
#define VMCNT0() asm volatile("s_waitcnt vmcnt(0)" ::: "memory")
#define BARRIER() do { asm volatile("" ::: "memory"); __builtin_amdgcn_s_barrier(); asm volatile("" ::: "memory"); } while (0)
#define MFMA16(d, a, b) d = __builtin_amdgcn_mfma_f32_16x16x32_bf16(a, b, d, 0, 0, 0)

__device__ __forceinline__ unsigned short f2bf(float f) {
    union { float f; unsigned int u; } v; v.f = f;
    unsigned int u = v.u;
    return (unsigned short)((u + 0x7FFFu + ((u >> 16) & 1u)) >> 16);  // RNE
}

// HW packed convert: dst.lo = bf16(a), dst.hi = bf16(b)
__device__ __forceinline__ unsigned int pk2bf(float a, float b) {
    unsigned int r;
    asm("v_cvt_pk_bf16_f32 %0, %1, %2" : "=v"(r) : "v"(a), "v"(b));
    return r;
}

// async global->LDS, 16B per lane. LDS dest is wave-uniform base + lane*16.
__device__ __forceinline__ void gload16(const void* g, void* l) {
    __builtin_amdgcn_global_load_lds(
        (__attribute__((address_space(1))) void*)(uintptr_t)g,
        (__attribute__((address_space(3))) void*)(uint32_t)(uintptr_t)l,
        16, 0, 0);
}

// ---------------- prep kernels ----------------

__global__ __launch_bounds__(256) void cvt_bf16_kernel(
    const float4* __restrict__ in, us4* __restrict__ out, int n4) {
    int i = blockIdx.x * 256 + threadIdx.x;
    if (i >= n4) return;
    float4 v = in[i];
    us4 o; o[0] = f2bf(v.x); o[1] = f2bf(v.y); o[2] = f2bf(v.z); o[3] = f2bf(v.w);
    out[i] = o;
}

// generic: in [R][C] fp32 -> out [C][R] bf16
__global__ __launch_bounds__(256) void transpose_bf16(
    const float* __restrict__ in, ushort_t* __restrict__ out, int R, int C) {
    __shared__ float t[64][65];
    int c0 = blockIdx.x * 64, r0 = blockIdx.y * 64;
    int cc = threadIdx.x & 63, rr = threadIdx.x >> 6;
#pragma unroll
    for (int i = 0; i < 16; ++i) {
        int r = i * 4 + rr;
        t[r][cc] = in[(size_t)(r0 + r) * C + c0 + cc];
    }
    __syncthreads();
#pragma unroll
    for (int i = 0; i < 16; ++i) {
        int r = i * 4 + rr;
        out[(size_t)(c0 + r) * R + r0 + cc] = f2bf(t[cc][r]);
    }
}

// Wqkv transpose with Q/K head-dim bit-permutation: out col p pairs with p+16
// (orig pairs d,d+64). orig(p) = (p&15) | (((p>>5)&3)<<4) | (((p>>4)&1)<<6).
// QK^T is invariant to a consistent d-permutation of Q and K; V left unpermuted.
__global__ __launch_bounds__(256) void transpose_wqkv(
    const float* __restrict__ in /*[2048][6144]*/, ushort_t* __restrict__ out /*[6144][2048]*/) {
    __shared__ float t[64][65];
    int c0 = blockIdx.x * 64, r0 = blockIdx.y * 64;
    int cc = threadIdx.x & 63, rr = threadIdx.x >> 6;
    int n = c0 + cc;
    int which = n >> 11;
    int src = n;
    if (which < 2) {
        int h = (n >> 7) & 15, p = n & 127;
        int po = (p & 15) | (((p >> 5) & 3) << 4) | (((p >> 4) & 1) << 6);
        src = (which << 11) + (h << 7) + po;
    }
#pragma unroll
    for (int i = 0; i < 16; ++i) {
        int r = i * 4 + rr;
        t[r][cc] = in[(size_t)(r0 + r) * 6144 + src];
    }
    __syncthreads();
#pragma unroll
    for (int i = 0; i < 16; ++i) {
        int r = i * 4 + rr;
        out[(size_t)(c0 + r) * 2048 + r0 + cc] = f2bf(t[cc][r]);
    }
}

// rope table: [L][64] of (cos, sin)
__global__ __launch_bounds__(256) void rope_table_kernel(float2* __restrict__ rope) {
    int i = blockIdx.x * 256 + threadIdx.x;     // L*64 = 131072 exactly
    int l = i >> 6, j = i & 63;
    float inv = exp2f((float)j * -0.20762050593046f);  // 10000^(-j/64)
    float f = (float)l * inv;
    rope[i] = make_float2(cosf(f), sinf(f));
}

// ---------------- 256x256 8-phase GEMM: C[M][N] = A[M][K] * Bt[N][K]^T ----------------
// BK=64, 512 thr (8 waves, 2M x 4N), wave tile 128x64. LDS 128 KiB: 2 buffers x
// (A0|A1|B0|B1 halves of 128x64 bf16, XOR-swizzled rows). Counted vmcnt(6) at phases
// 4/8, raw s_barrier. LDS pins 1 block/CU; __launch_bounds__(512,1) lifts the VGPR cap
// (R8: min-waves=2 capped VGPR+AGPR at 256 -> 43MB/dispatch spill writes, MfmaUtil 20%).

template <int EPI>
__global__ __launch_bounds__(512, 1)
void gemm256(const ushort_t* __restrict__ A, const ushort_t* __restrict__ Bt,
             int M, int N, int K,
             float* __restrict__ C,
             ushort_t* __restrict__ Qb, ushort_t* __restrict__ Kb,
             ushort_t* __restrict__ Vt, const float2* __restrict__ rope) {
    __shared__ __attribute__((aligned(16))) char lds[131072];

    const int tid  = threadIdx.x;
    const int lane = tid & 63, wid = tid >> 6;
    const int lr = lane & 15, lg = lane >> 4;
    const int wr = wid >> 2, wc = wid & 3;        // wave grid 2(M) x 4(N)

    const int nbn = N >> 8;
    const int nwg = gridDim.x;
    const int bid = blockIdx.x;
    const int wg  = (bid & 7) * (nwg >> 3) + (bid >> 3);   // XCD-contiguous
    const int bm  = wg / nbn, bn = wg % nbn;

    // staging: chunk = 64 rows x 64 cols bf16 (8 KB = 512 thr x 16 B)
    const int srow = tid >> 3;                                   // 0..63
    const int scol = ((tid & 7) << 4) ^ ((srow & 7) << 4);       // pre-swizzled src col
    const char* Asrc = (const char*)A + ((size_t)(bm * 256 + srow) * K) * 2 + scol;
    const char* Bsrc = (const char*)Bt + ((size_t)(bn * 256 + srow) * K) * 2 + scol;
    const size_t rowK2 = (size_t)K * 2;

    // reg: 0=A0,1=A1,2=B0,3=B1 (each 16 KB); ch: 0/1 (64-row chunk); kt: K-tile
    auto STG = [&](int bu, int reg, int ch, int kt) {
        const char* s = (reg < 2 ? Asrc : Bsrc) +
                        (size_t)((reg & 1) * 128 + ch * 64) * rowK2 + (size_t)kt * 128;
        gload16(s, lds + bu * 65536 + reg * 16384 + ch * 8192 + wid * 1024);
    };
    auto RDA = [&](int bu, int mi, int kk) -> bf16x8 {
        int rowl = mi * 16 + lr;                                 // within wave's A-half
        int off = (rowl << 7) + kk * 64 + lg * 16;
        off ^= (rowl & 7) << 4;
        return *(const bf16x8*)(lds + bu * 65536 + wr * 16384 + off);
    };
    auto RDB = [&](int bu, int ni, int kk) -> bf16x8 {
        int rowb = wc * 64 + ni * 16 + lr;                       // 0..255
        int off = ((rowb & 127) << 7) + kk * 64 + lg * 16;
        off ^= (rowb & 7) << 4;
        return *(const bf16x8*)(lds + bu * 65536 + 32768 + (rowb >> 7) * 16384 + off);
    };

    f32x4 acc[8][4];
#pragma unroll
    for (int m = 0; m < 8; ++m)
#pragma unroll
        for (int n = 0; n < 4; ++n) acc[m][n] = (f32x4){0.f, 0.f, 0.f, 0.f};

    bf16x8 aLo[4][2], aHi[4][2], bF[2][2];

    // ---- prologue: tile0 fully (8 chunks) + tile1 A+B0 (6 chunks) ----
#pragma unroll
    for (int reg = 0; reg < 4; ++reg) { STG(0, reg, 0, 0); STG(0, reg, 1, 0); }
#pragma unroll
    for (int reg = 0; reg < 3; ++reg) { STG(1, reg, 0, 1); STG(1, reg, 1, 1); }
    VMCNT6();
    BARRIER();

    const int NIT = K / 128;                     // iterations (2 K-tiles each)
    for (int i = 0; i < NIT; ++i) {
        const int te = 2 * i, to = 2 * i + 1;
        const bool g = (i + 1 < NIT);

        // P1: tile te quadrant (mi0-3, ni0-1); stage buf1.B1 of tile 'to'
#pragma unroll
        for (int m = 0; m < 4; ++m) { aLo[m][0] = RDA(0, m, 0); aLo[m][1] = RDA(0, m, 1); }
#pragma unroll
        for (int n = 0; n < 2; ++n) { bF[n][0] = RDB(0, n, 0); bF[n][1] = RDB(0, n, 1); }
        STG(1, 3, 0, to); STG(1, 3, 1, to);
        BARRIER();
        __builtin_amdgcn_s_setprio(1);
#pragma unroll
        for (int kk = 0; kk < 2; ++kk)
#pragma unroll
            for (int m = 0; m < 4; ++m)
#pragma unroll
                for (int n = 0; n < 2; ++n) MFMA16(acc[m][n], aLo[m][kk], bF[n][kk]);
        __builtin_amdgcn_s_setprio(0);
        BARRIER();

        // P2: (mi4-7, ni0-1); stage buf0.A0c0, A1c0 of te+2
#pragma unroll
        for (int m = 0; m < 4; ++m) { aHi[m][0] = RDA(0, 4 + m, 0); aHi[m][1] = RDA(0, 4 + m, 1); }
        if (g) { STG(0, 0, 0, te + 2); STG(0, 1, 0, te + 2); }
        BARRIER();
        __builtin_amdgcn_s_setprio(1);
#pragma unroll
        for (int kk = 0; kk < 2; ++kk)
#pragma unroll
            for (int m = 0; m < 4; ++m)
#pragma unroll
                for (int n = 0; n < 2; ++n) MFMA16(acc[4 + m][n], aHi[m][kk], bF[n][kk]);
        __builtin_amdgcn_s_setprio(0);
        BARRIER();

        // P3: (mi0-3, ni2-3); stage buf0.A0c1, A1c1 of te+2
#pragma unroll
        for (int n = 0; n < 2; ++n) { bF[n][0] = RDB(0, 2 + n, 0); bF[n][1] = RDB(0, 2 + n, 1); }
        if (g) { STG(0, 0, 1, te + 2); STG(0, 1, 1, te + 2); }
        BARRIER();
        __builtin_amdgcn_s_setprio(1);
#pragma unroll
        for (int kk = 0; kk < 2; ++kk)
#pragma unroll
            for (int m = 0; m < 4; ++m)
#pragma unroll
                for (int n = 0; n < 2; ++n) MFMA16(acc[m][2 + n], aLo[m][kk], bF[n][kk]);
        __builtin_amdgcn_s_setprio(0);
        BARRIER();

        // P4: (mi4-7, ni2-3); stage buf0.B0 chunks of te+2; vmcnt -> buf1 tile 'to' ready
        if (g) { STG(0, 2, 0, te + 2); STG(0, 2, 1, te + 2); VMCNT6(); } else { VMCNT0(); }
        BARRIER();
        __builtin_amdgcn_s_setprio(1);
#pragma unroll
        for (int kk = 0; kk < 2; ++kk)
#pragma unroll
            for (int m = 0; m < 4; ++m)
#pragma unroll
                for (int n = 0; n < 2; ++n) MFMA16(acc[4 + m][2 + n], aHi[m][kk], bF[n][kk]);
        __builtin_amdgcn_s_setprio(0);
        BARRIER();

        // P5: tile to (buf1) quadrant (mi0-3, ni0-1); stage buf0.B1 of te+2
#pragma unroll
        for (int m = 0; m < 4; ++m) { aLo[m][0] = RDA(1, m, 0); aLo[m][1] = RDA(1, m, 1); }
#pragma unroll
        for (int n = 0; n < 2; ++n) { bF[n][0] = RDB(1, n, 0); bF[n][1] = RDB(1, n, 1); }
        if (g) { STG(0, 3, 0, te + 2); STG(0, 3, 1, te + 2); }
        BARRIER();
        __builtin_amdgcn_s_setprio(1);
#pragma unroll
        for (int kk = 0; kk < 2; ++kk)
#pragma unroll
            for (int m = 0; m < 4; ++m)
#pragma unroll
                for (int n = 0; n < 2; ++n) MFMA16(acc[m][n], aLo[m][kk], bF[n][kk]);
        __builtin_amdgcn_s_setprio(0);
        BARRIER();

        // P6: (mi4-7, ni0-1); stage buf1.A0c0, A1c0 of to+2
#pragma unroll
        for (int m = 0; m < 4; ++m) { aHi[m][0] = RDA(1, 4 + m, 0); aHi[m][1] = RDA(1, 4 + m, 1); }
        if (g) { STG(1, 0, 0, to + 2); STG(1, 1, 0, to + 2); }
        BARRIER();
        __builtin_amdgcn_s_setprio(1);
#pragma unroll
        for (int kk = 0; kk < 2; ++kk)
#pragma unroll
            for (int m = 0; m < 4; ++m)
#pragma unroll
                for (int n = 0; n < 2; ++n) MFMA16(acc[4 + m][n], aHi[m][kk], bF[n][kk]);
        __builtin_amdgcn_s_setprio(0);
        BARRIER();

        // P7: (mi0-3, ni2-3); stage buf1.A0c1, A1c1 of to+2
#pragma unroll
        for (int n = 0; n < 2; ++n) { bF[n][0] = RDB(1, 2 + n, 0); bF[n][1] = RDB(1, 2 + n, 1); }
        if (g) { STG(1, 0, 1, to + 2); STG(1, 1, 1, to + 2); }
        BARRIER();
        __builtin_amdgcn_s_setprio(1);
#pragma unroll
        for (int kk = 0; kk < 2; ++kk)
#pragma unroll
            for (int m = 0; m < 4; ++m)
#pragma unroll
                for (int n = 0; n < 2; ++n) MFMA16(acc[m][2 + n], aLo[m][kk], bF[n][kk]);
        __builtin_amdgcn_s_setprio(0);
        BARRIER();

        // P8: (mi4-7, ni2-3); stage buf1.B0 of to+2; vmcnt -> buf0 tile te+2 ready
        if (g) { STG(1, 2, 0, to + 2); STG(1, 2, 1, to + 2); VMCNT6(); } else { VMCNT0(); }
        BARRIER();
        __builtin_amdgcn_s_setprio(1);
#pragma unroll
        for (int kk = 0; kk < 2; ++kk)
#pragma unroll
            for (int m = 0; m < 4; ++m)
#pragma unroll
                for (int n = 0; n < 2; ++n) MFMA16(acc[4 + m][2 + n], aHi[m][kk], bF[n][kk]);
        __builtin_amdgcn_s_setprio(0);
        BARRIER();
    }

    // ---------------- epilogue ----------------
    if constexpr (EPI == 0) {
#pragma unroll
        for (int m = 0; m < 8; ++m) {
            int gr0 = bm * 256 + wr * 128 + m * 16 + lg * 4;
#pragma unroll
            for (int n = 0; n < 4; ++n) {
                int gc = bn * 256 + wc * 64 + n * 16 + lr;
#pragma unroll
                for (int r = 0; r < 4; ++r)
                    C[(size_t)(gr0 + r) * N + gc] = acc[m][n][r];
            }
        }
    } else {
        // head-chunk: 128 N-cols; wave covers 64 of them ((wc&1) half)
        const int hc = bn * 2 + (wc >> 1);       // 0..47
        const int which = hc >> 4, h = hc & 15;
#pragma unroll
        for (int m = 0; m < 8; ++m) {
            int gr0 = bm * 256 + wr * 128 + m * 16 + lg * 4;   // b*L + l0
            int b = gr0 >> 11, l0 = gr0 & 2047;
            if (which == 2) {                    // V -> [BH][D][L], d unpermuted
#pragma unroll
                for (int n = 0; n < 4; ++n) {
                    int d = (wc & 1) * 64 + n * 16 + lr;
                    us4 pk;
#pragma unroll
                    for (int r = 0; r < 4; ++r) pk[r] = f2bf(acc[m][n][r]);
                    *(us4*)(Vt + ((size_t)(b * 16 + h) * 128 + d) * 2048 + l0) = pk;
                }
            } else {                             // Q/K: rope on lane-local pairs (np, np+1)
                ushort_t* dst = (which == 0) ? Qb : Kb;
                const float sc = (which == 0) ? QK_SCALE : 1.0f;
#pragma unroll
                for (int np = 0; np < 4; np += 2) {
                    int tbl = ((wc & 1) * 2 + (np >> 1)) * 16 + lr;   // orig dim 0..63
                    int p1 = (wc & 1) * 64 + np * 16 + lr;            // permuted d
#pragma unroll
                    for (int r = 0; r < 4; ++r) {
                        float2 cs = rope[(size_t)(l0 + r) * 64 + tbl];
                        float x1 = acc[m][np][r], x2 = acc[m][np + 1][r];
                        size_t base = ((size_t)(b * 16 + h) * 2048 + (l0 + r)) * 128;
                        dst[base + p1]      = f2bf((x1 * cs.x - x2 * cs.y) * sc);
                        dst[base + p1 + 16] = f2bf((x2 * cs.x + x1 * cs.y) * sc);
                    }
                }
            }
        }
    }
}

// ---------------- causal flash attention (R6 kernel, verified 266 us) ----------------
__global__ __attribute__((amdgpu_flat_work_group_size(64, 64), amdgpu_waves_per_eu(2, 2)))
void attn_fwd(const ushort_t* __restrict__ Qb, const ushort_t* __restrict__ Kb,
              const ushort_t* __restrict__ Vt, ushort_t* __restrict__ AO) {
    constexpr int L = 2048;
    const int lane = threadIdx.x;
    const int q_l  = lane & 31;
    const int hi   = lane >> 5;

    const int bid  = blockIdx.x;
    const int j    = bid >> 3;
    const int hl   = j & 7;
    const int rank = j >> 3;                    // 0..63
    const int head = (bid & 7) * 8 + hl;
    const int sl   = 63 - rank;
    const int q0   = sl * 32;

    const ushort_t* Qh = Qb + (size_t)head * L * 128;
    const ushort_t* Kh = Kb + (size_t)head * L * 128;
    const ushort_t* Vh = Vt + (size_t)head * 128 * L;
    const int b = head >> 4, h = head & 15;

    bf16x8 qf[8];
#pragma unroll
    for (int sb = 0; sb < 8; ++sb)
        qf[sb] = *(const bf16x8*)(Qh + (size_t)(q0 + q_l) * 128 + sb * 16 + hi * 8);

    f32x16 o[4];
#pragma unroll
    for (int d0 = 0; d0 < 4; ++d0) o[d0] = (f32x16)(0.f);
    float m_ = -__builtin_inff(), l_ = 0.f;

    bf16x8 kf[8];
#pragma unroll
    for (int sb = 0; sb < 8; ++sb)
        kf[sb] = *(const bf16x8*)(Kh + (size_t)q_l * 128 + sb * 16 + hi * 8);

    const int ntile = sl + 1;
    for (int t = 0; t < ntile; ++t) {
        const int k0 = t * 32;

        bf16x8 vf[8];
#pragma unroll
        for (int d0 = 0; d0 < 4; ++d0)
#pragma unroll
            for (int ks = 0; ks < 2; ++ks)
                vf[d0 * 2 + ks] = *(const bf16x8*)(Vh + (size_t)(d0 * 32 + q_l) * L + k0 + ks * 16 + hi * 8);

        f32x16 sa = (f32x16)(0.f), sb2 = (f32x16)(0.f);
#pragma unroll
        for (int sb = 0; sb < 8; sb += 2) {
            sa  = __builtin_amdgcn_mfma_f32_32x32x16_bf16(kf[sb],     qf[sb],     sa,  0, 0, 0);
            sb2 = __builtin_amdgcn_mfma_f32_32x32x16_bf16(kf[sb + 1], qf[sb + 1], sb2, 0, 0, 0);
        }
        f32x16 s = sa + sb2;

        if (t + 1 < ntile) {
            const int kn = k0 + 32;
#pragma unroll
            for (int sb = 0; sb < 8; ++sb)
                kf[sb] = *(const bf16x8*)(Kh + (size_t)(kn + q_l) * 128 + sb * 16 + hi * 8);
        }

        if (t == ntile - 1) {
#pragma unroll
            for (int r = 0; r < 16; ++r) {
                int kk = (r & 3) + 8 * (r >> 2) + 4 * hi;
                if (kk > q_l) s[r] = NEG_BIG;
            }
        }

        float t8[8];
#pragma unroll
        for (int r = 0; r < 8; ++r) t8[r] = fmaxf(s[r], s[r + 8]);
#pragma unroll
        for (int r = 0; r < 4; ++r) t8[r] = fmaxf(t8[r], t8[r + 4]);
        float tmax = fmaxf(fmaxf(t8[0], t8[1]), fmaxf(t8[2], t8[3]));
        tmax = fmaxf(tmax, __shfl_xor(tmax, 32, 64));

        if (!__all(tmax <= m_ + 8.f)) {
            float mn = fmaxf(m_, tmax);
            float alpha = exp2f(m_ - mn);
            m_ = mn;
            l_ *= alpha;
#pragma unroll
            for (int d0 = 0; d0 < 4; ++d0)
#pragma unroll
                for (int r = 0; r < 16; ++r) o[d0][r] *= alpha;
        }

        float p[16];
        float rs = 0.f;
#pragma unroll
        for (int r = 0; r < 16; ++r) { p[r] = exp2f(s[r] - m_); rs += p[r]; }
        rs += __shfl_xor(rs, 32, 64);
        l_ += rs;

        unsigned int pk[8];
#pragma unroll
        for (int i = 0; i < 8; ++i) pk[i] = pk2bf(p[2 * i], p[2 * i + 1]);
        unsigned int po[8];
#pragma unroll
        for (int i = 0; i < 8; ++i) po[i] = __shfl_xor(pk[i], 32, 64);

        bf16x8 pf[2];
#pragma unroll
        for (int ks = 0; ks < 2; ++ks) {
            ui4 dw;
            dw[0] = hi ? po[ks * 4 + 2] : pk[ks * 4 + 0];
            dw[1] = hi ? po[ks * 4 + 3] : pk[ks * 4 + 1];
            dw[2] = hi ? pk[ks * 4 + 2] : po[ks * 4 + 0];
            dw[3] = hi ? pk[ks * 4 + 3] : po[ks * 4 + 1];
            pf[ks] = __builtin_bit_cast(bf16x8, dw);
        }

#pragma unroll
        for (int d0 = 0; d0 < 4; ++d0)
#pragma unroll
            for (int ks = 0; ks < 2; ++ks)
                o[d0] = __builtin_amdgcn_mfma_f32_32x32x16_bf16(vf[d0 * 2 + ks], pf[ks], o[d0], 0, 0, 0);
    }

    const float inv = 1.f / l_;
    const size_t rowbase = ((size_t)(b * 2048 + q0 + q_l)) * 2048 + h * 128;
#pragma unroll
    for (int d0 = 0; d0 < 4; ++d0)
#pragma unroll
        for (int g = 0; g < 4; ++g) {
            us4 v;
#pragma unroll
            for (int r = 0; r < 4; ++r) v[r] = f2bf(o[d0][g * 4 + r] * inv);
            *(us4*)(AO + rowbase + d0 * 32 + g * 8 + hi * 4) = v;
        }
}

// ---------------- launcher ----------------

extern "C" void kernel_launch(void* const* d_in, const int* in_sizes, int n_in,
                              void* d_out, int out_size, void* d_ws, size_t ws_size,
                              hipStream_t stream) {
    const float* x    = (const float*)d_in[0];   // [4,2048,2048]
    const float* Wqkv = (const float*)d_in[1];   // [2048,6144]
    const float* Wo   = (const float*)d_in[2];   // [2048,2048]
    float* out = (float*)d_out;                  // [4,2048,2048] fp32

    char* w = (char*)d_ws;
    ushort_t* xb   = (ushort_t*)(w);               // x bf16             33,554,432 B
    ushort_t* W1t  = (ushort_t*)(w + 33554432);    // Wqkv^T bf16 (QK-permuted) 25,165,824 B
    ushort_t* Wot  = (ushort_t*)(w + 58720256);    // Wo^T bf16           8,388,608 B
    ushort_t* Qb   = (ushort_t*)(w + 67108864);    // Q roped [BH][L][D'] 33,554,432 B
    ushort_t* Kbf  = (ushort_t*)(w + 100663296);   // K roped [BH][L][D'] 33,554,432 B
    ushort_t* Vt   = (ushort_t*)(w + 134217728);   // V^T    [BH][D][L]  33,554,432 B
    ushort_t* AO   = (ushort_t*)(w + 167772160);   // attn out bf16      33,554,432 B
    float2*   rope = (float2*)(w + 201326592);     // [L][64] cos/sin     1,048,576 B

    cvt_bf16_kernel<<<16384, 256, 0, stream>>>((const float4*)x, (us4*)xb, 4194304);
    transpose_wqkv<<<dim3(96, 32), 256, 0, stream>>>(Wqkv, W1t);
    transpose_bf16<<<dim3(32, 32), 256, 0, stream>>>(Wo, Wot, 2048, 2048);
    rope_table_kernel<<<512, 256, 0, stream>>>(rope);

    // qkv GEMM (256^2 8-phase) + fused rope/reshape epilogue
    gemm256<1><<<768, 512, 0, stream>>>(xb, W1t, 8192, 6144, 2048,
                                        nullptr, Qb, Kbf, Vt, rope);
    // causal flash attention (R6 config)
    attn_fwd<<<4096, 64, 0, stream>>>(Qb, Kbf, Vt, AO);
    // output projection (256^2 8-phase)
    gemm256<0><<<256, 512, 0, stream>>>(AO, Wot, 8192, 2048, 2048,
                                        out, nullptr, nullptr, nullptr, nullptr);
}